// Round 3
// baseline (109.063 us; speedup 1.0000x reference)
//
#include <hip/hip_runtime.h>

// SPU bound transformer: element-wise over (N,2) fp32 rows.
// Pure stream: 67 MB in + 67 MB out. Memory-bound.
//
// v4 = v3 arithmetic (div-free select, rcp sigmoid) + ONE isolated memory
// change: ILP=4. Each block owns a contiguous 16 KB chunk (1024 float4s);
// each thread issues 4 plain coalesced loads (+0,+256,+512,+768 float4s),
// computes, then 4 stores. No NT hints (R1 showed NT/far-strided streams
// regress kernel time +50%). Dense per-block footprint keeps the wavefront
// of requests contiguous, unlike R1's 16 MB-separated streams.

typedef float f32x4 __attribute__((ext_vector_type(4)));

__device__ __forceinline__ float spu_f(float x) {
    // x >= 0: x*x - 0.5
    // x <  0: sigmoid(-x) - 1 = -e^x / (1 + e^x)
    float t = __expf(x);                                // v_exp_f32 (+mul)
    float negbr = -t * __builtin_amdgcn_rcpf(1.0f + t); // v_rcp_f32
    float posbr = __fmaf_rn(x, x, -0.5f);
    return (x >= 0.0f) ? posbr : negbr;
}

__device__ __forceinline__ f32x4 spu_pair(f32x4 v) {
    f32x4 r;
    #pragma unroll
    for (int k = 0; k < 2; ++k) {
        float l = (k == 0) ? v.x : v.z;
        float u = (k == 0) ? v.y : v.w;
        float vl = spu_f(l);
        float vu = spu_f(u);
        bool neg   = (u <= 0.0f);
        bool pos   = (l >= 0.0f);
        bool cross = !(neg || pos);
        // cross => l < 0 < u => u - l > 0, so slope >= 0 <=> vu >= vl.
        bool cpos  = cross && (vu >= vl);
        bool cneg  = cross && (vu <  vl);
        float lo = neg ? vl : (cpos ? -0.5f : 0.0f);
        float up = neg ? vu : (cpos ? vu : (cneg ? vl : 0.0f));
        if (k == 0) { r.x = lo; r.y = up; }
        else        { r.z = lo; r.w = up; }
    }
    return r;
}

__global__ __launch_bounds__(256) void spu_kernel(const f32x4* __restrict__ in,
                                                  f32x4* __restrict__ out,
                                                  int n4) {
    // Block-local dense chunk: 1024 float4s = 16 KB per block.
    int base = blockIdx.x * 1024 + threadIdx.x;
    int i0 = base;
    int i1 = base + 256;
    int i2 = base + 512;
    int i3 = base + 768;
    if (i3 < n4) {
        // Fast path (always taken for n4 = 4194304): 4 loads in flight.
        f32x4 a = in[i0];
        f32x4 b = in[i1];
        f32x4 c = in[i2];
        f32x4 d = in[i3];
        f32x4 ra = spu_pair(a);
        f32x4 rb = spu_pair(b);
        f32x4 rc = spu_pair(c);
        f32x4 rd = spu_pair(d);
        out[i0] = ra;
        out[i1] = rb;
        out[i2] = rc;
        out[i3] = rd;
    } else {
        if (i0 < n4) out[i0] = spu_pair(in[i0]);
        if (i1 < n4) out[i1] = spu_pair(in[i1]);
        if (i2 < n4) out[i2] = spu_pair(in[i2]);
    }
}

extern "C" void kernel_launch(void* const* d_in, const int* in_sizes, int n_in,
                              void* d_out, int out_size, void* d_ws, size_t ws_size,
                              hipStream_t stream) {
    const f32x4* in = (const f32x4*)d_in[0];
    f32x4* out = (f32x4*)d_out;
    int n4 = out_size / 4;                 // 8388608*2 floats / 4 = 4194304
    int threads = 256;
    int per_block = threads * 4;           // 1024 float4s per block
    int blocks = (n4 + per_block - 1) / per_block;   // 4096
    spu_kernel<<<blocks, threads, 0, stream>>>(in, out, n4);
}